// Round 1
// 106.766 us; speedup vs baseline: 1.0696x; 1.0696x over previous
//
#include <hip/hip_runtime.h>
#include <hip/hip_bf16.h>

#define Bn 4096
#define Dk 1024
#define EPSF 1e-7f

typedef float f32x16 __attribute__((ext_vector_type(16)));
typedef int i32x4 __attribute__((ext_vector_type(4)));
typedef int i32x8 __attribute__((ext_vector_type(8)));

__device__ __forceinline__ void async_copy16(const void* g, void* l) {
    __builtin_amdgcn_global_load_lds((__attribute__((address_space(1))) void*)(uintptr_t)g,
                                     (__attribute__((address_space(3))) void*)l, 16, 0, 0);
}

// -------- Kernel 1: L2-normalize -> fp8 e4m3 (x8 prescale), PLAIN row-major layout ----
// The 32x32x64 scaled MFMA consumes 32 contiguous k-bytes per lane; A and B share the
// same lane->k mapping, so plain k-order for both operands keeps dot products exact.
// (The old 16x16x32 K-interleave is gone.)
__global__ __launch_bounds__(256)
void nrm_kernel(const float4* __restrict__ left, const float4* __restrict__ right,
                unsigned char* __restrict__ lnb8, unsigned char* __restrict__ rnb8,
                float* __restrict__ diag, float* __restrict__ rowsum,
                float* __restrict__ colsum)
{
    const int row = blockIdx.x;
    const int t = threadIdx.x;
    const int idx = row * (Dk / 4) + t;
    const float4 l = left[idx];
    const float4 r = right[idx];
    float sl = l.x * l.x + l.y * l.y + l.z * l.z + l.w * l.w;
    float sr = r.x * r.x + r.y * r.y + r.z * r.z + r.w * r.w;
    float slr = l.x * r.x + l.y * r.y + l.z * r.z + l.w * r.w;
    #pragma unroll
    for (int off = 1; off < 64; off <<= 1) {
        sl += __shfl_xor(sl, off);
        sr += __shfl_xor(sr, off);
        slr += __shfl_xor(slr, off);
    }
    __shared__ float red[3][4];
    const int wave = t >> 6, lane = t & 63;
    if (lane == 0) { red[0][wave] = sl; red[1][wave] = sr; red[2][wave] = slr; }
    __syncthreads();
    sl = red[0][0] + red[0][1] + red[0][2] + red[0][3];
    sr = red[1][0] + red[1][1] + red[1][2] + red[1][3];
    const float invl = 1.0f / sqrtf(fmaxf(sl, EPSF));
    const float invr = 1.0f / sqrtf(fmaxf(sr, EPSF));
    const float sL = 8.0f * invl;
    const float sR = 8.0f * invr;
    int pkL = __builtin_amdgcn_cvt_pk_fp8_f32(l.x * sL, l.y * sL, 0, false);
    pkL = __builtin_amdgcn_cvt_pk_fp8_f32(l.z * sL, l.w * sL, pkL, true);
    int pkR = __builtin_amdgcn_cvt_pk_fp8_f32(r.x * sR, r.y * sR, 0, false);
    pkR = __builtin_amdgcn_cvt_pk_fp8_f32(r.z * sR, r.w * sR, pkR, true);
    const int dst = row * Dk + 4 * t;   // plain row-major k-order
    *(unsigned*)(lnb8 + dst) = (unsigned)pkL;
    *(unsigned*)(rnb8 + dst) = (unsigned)pkR;
    if (t == 0) {
        const float d = red[2][0] + red[2][1] + red[2][2] + red[2][3];
        diag[row] = d * invl * invr;
        rowsum[row] = 0.f;
        colsum[row] = 0.f;
    }
}

// -------- Kernel 2: S = ln . rn^T via MX-scaled fp8 MFMA (scale == 1.0, bit-neutral) ----
// Same proven skeleton as the 16x16x32 version (R10 optimum): 128x256 block tile,
// ping-pong LDS, raw "s_waitcnt vmcnt(6); s_barrier" (prefetch stays in flight across
// the barrier), execution-only post-barrier, granule XOR-swizzle g^((row>>1)&3) on the
// staging source (verified conflict-free for the new 2x b128-per-fragment reads).
// Change: compute runs on mfma_scale_f32_32x32x64_f8f6f4 (4.69 PF pipe, 2x the
// non-scaled fp8 rate) with E8M0 scale byte 127 (= 2^0) on all lanes.
__global__ __launch_bounds__(256, 2)
void gemm_sm_kernel(const unsigned char* __restrict__ lnb8,
                    const unsigned char* __restrict__ rnb8,
                    const float* __restrict__ temp,
                    float* __restrict__ rowsum, float* __restrict__ colsum)
{
    __shared__ __align__(16) unsigned char As[2][128 * 64];
    __shared__ __align__(16) unsigned char Bs[2][256 * 64];

    const int tid = threadIdx.x;
    const int wave = tid >> 6;
    const int lane = tid & 63;
    const int bm0 = blockIdx.y * 128;
    const int bn0 = blockIdx.x * 256;

    // ---- staging: wave stages A rows [32w,32w+32) (2 insts) and B rows [64w,64w+64) (4 insts)
    const int srow = lane >> 2;
    const int sj = lane & 3;
    int goffA[2], lofsA[2];
    #pragma unroll
    for (int i = 0; i < 2; ++i) {
        const int rloc = wave * 32 + i * 16 + srow;
        goffA[i] = rloc * Dk + 16 * (sj ^ ((rloc >> 1) & 3));
        lofsA[i] = (wave * 32 + i * 16) * 64;
    }
    int goffB[4], lofsB[4];
    #pragma unroll
    for (int i = 0; i < 4; ++i) {
        const int rloc = wave * 64 + i * 16 + srow;
        goffB[i] = rloc * Dk + 16 * (sj ^ ((rloc >> 1) & 3));
        lofsB[i] = (wave * 64 + i * 16) * 64;
    }
    const unsigned char* baseA = lnb8 + (size_t)bm0 * Dk;
    const unsigned char* baseB = rnb8 + (size_t)bn0 * Dk;

    // ---- compute-side: wave tile 64x128 as 2x4 grid of 32x32 tiles
    const int wm = (wave & 1) * 64;
    const int wn = (wave >> 1) * 128;
    const int r32 = lane & 31;
    const int h = lane >> 5;     // k-half of the 64-byte K-tile
    int aoff[2][2], boff[4][2];
    #pragma unroll
    for (int mi = 0; mi < 2; ++mi) {
        const int row = wm + mi * 32 + r32;
        const int key = (row >> 1) & 3;
        aoff[mi][0] = row * 64 + 16 * ((2 * h) ^ key);
        aoff[mi][1] = row * 64 + 16 * ((2 * h + 1) ^ key);
    }
    #pragma unroll
    for (int ni = 0; ni < 4; ++ni) {
        const int row = wn + ni * 32 + r32;
        const int key = (row >> 1) & 3;
        boff[ni][0] = row * 64 + 16 * ((2 * h) ^ key);
        boff[ni][1] = row * 64 + 16 * ((2 * h + 1) ^ key);
    }

    f32x16 acc[2][4];
    #pragma unroll
    for (int mi = 0; mi < 2; ++mi)
        #pragma unroll
        for (int ni = 0; ni < 4; ++ni)
            #pragma unroll
            for (int r = 0; r < 16; ++r)
                acc[mi][ni][r] = 0.f;

    // prologue: stage tile 0 into buffer 0
    #pragma unroll
    for (int i = 0; i < 2; ++i) async_copy16(baseA + goffA[i], &As[0][lofsA[i]]);
    #pragma unroll
    for (int i = 0; i < 4; ++i) async_copy16(baseB + goffB[i], &Bs[0][lofsB[i]]);

    #pragma unroll 2
    for (int it = 0; it < 16; ++it) {
        const int cur = it & 1;
        const int nxt = cur ^ 1;
        const int knext = ((it + 1) & 15) * 64;   // wraps on last iter (dummy reload)
        #pragma unroll
        for (int i = 0; i < 2; ++i) async_copy16(baseA + goffA[i] + knext, &As[nxt][lofsA[i]]);
        #pragma unroll
        for (int i = 0; i < 4; ++i) async_copy16(baseB + goffB[i] + knext, &Bs[nxt][lofsB[i]]);
        // wait only the PREVIOUS tile's 6 loads; prefetch stays in flight
        asm volatile("s_waitcnt vmcnt(6)\n\ts_barrier" ::: "memory");
        i32x8 af[2], bf[4];
        #pragma unroll
        for (int mi = 0; mi < 2; ++mi) {
            const i32x4 lo = *(const i32x4*)(&As[cur][aoff[mi][0]]);
            const i32x4 hi = *(const i32x4*)(&As[cur][aoff[mi][1]]);
            af[mi] = __builtin_shufflevector(lo, hi, 0, 1, 2, 3, 4, 5, 6, 7);
        }
        #pragma unroll
        for (int ni = 0; ni < 4; ++ni) {
            const i32x4 lo = *(const i32x4*)(&Bs[cur][boff[ni][0]]);
            const i32x4 hi = *(const i32x4*)(&Bs[cur][boff[ni][1]]);
            bf[ni] = __builtin_shufflevector(lo, hi, 0, 1, 2, 3, 4, 5, 6, 7);
        }
        #pragma unroll
        for (int mi = 0; mi < 2; ++mi)
            #pragma unroll
            for (int ni = 0; ni < 4; ++ni)
                acc[mi][ni] = __builtin_amdgcn_mfma_scale_f32_32x32x64_f8f6f4(
                    af[mi], bf[ni], acc[mi][ni],
                    0, 0,                       // cbsz=fp8(e4m3), blgp=fp8(e4m3)
                    0, 0x7f7f7f7f,              // A scale: E8M0 127 -> 2^0 = 1.0
                    0, 0x7f7f7f7f);             // B scale: 1.0
        // execution-only barrier: everyone done reading `cur` before it is restaged
        asm volatile("s_barrier" ::: "memory");
    }

    // epilogue: undo the 8x8 prescale (2^-6, exact), then p = exp(scale*s - scale)
    const float scale = __expf(temp[0]);
    const float dq = 0.015625f * scale;  // 2^-6 * scale
    #pragma unroll
    for (int mi = 0; mi < 2; ++mi)
        #pragma unroll
        for (int ni = 0; ni < 4; ++ni)
            #pragma unroll
            for (int r = 0; r < 16; ++r)
                acc[mi][ni][r] = __expf(dq * acc[mi][ni][r] - scale);

    // 32x32 C/D layout: col = lane&31, row = (reg&3) + 8*(reg>>2) + 4*(lane>>5)
    // row sums: reduce over cols (butterfly within each 32-lane half)
    #pragma unroll
    for (int mi = 0; mi < 2; ++mi) {
        #pragma unroll
        for (int r = 0; r < 16; ++r) {
            float v = acc[mi][0][r] + acc[mi][1][r] + acc[mi][2][r] + acc[mi][3][r];
            v += __shfl_xor(v, 1);
            v += __shfl_xor(v, 2);
            v += __shfl_xor(v, 4);
            v += __shfl_xor(v, 8);
            v += __shfl_xor(v, 16);
            if (r32 == 0)
                atomicAdd(&rowsum[bm0 + wm + mi * 32 + (r & 3) + 8 * (r >> 2) + 4 * h], v);
        }
    }
    // col sums: each lane owns col r32; sum its 32 rows, then combine the two halves
    #pragma unroll
    for (int ni = 0; ni < 4; ++ni) {
        float v = 0.f;
        #pragma unroll
        for (int mi = 0; mi < 2; ++mi)
            #pragma unroll
            for (int r = 0; r < 16; ++r)
                v += acc[mi][ni][r];
        v += __shfl_xor(v, 32);
        if (h == 0)
            atomicAdd(&colsum[bn0 + wn + ni * 32 + r32], v);
    }
}

// -------- Kernel 3: final scalar loss --------
__global__ __launch_bounds__(256)
void loss_kernel(const float* __restrict__ diag, const float* __restrict__ rowsum,
                 const float* __restrict__ colsum, const float* __restrict__ temp,
                 float* __restrict__ out)
{
    const int t = threadIdx.x;
    const float scale = __expf(temp[0]);
    float dL = 0.f, dR = 0.f;
    for (int i = t; i < Bn; i += 256) {
        const float e = __expf(scale * (diag[i] - 1.0f));
        dL += e * __builtin_amdgcn_rcpf(rowsum[i]);
        dR += e * __builtin_amdgcn_rcpf(colsum[i]);
    }
    #pragma unroll
    for (int off = 1; off < 64; off <<= 1) {
        dL += __shfl_xor(dL, off);
        dR += __shfl_xor(dR, off);
    }
    __shared__ float rd[2][4];
    const int wave = t >> 6, lane = t & 63;
    if (lane == 0) { rd[0][wave] = dL; rd[1][wave] = dR; }
    __syncthreads();
    if (t == 0) {
        dL = rd[0][0] + rd[0][1] + rd[0][2] + rd[0][3];
        dR = rd[1][0] + rd[1][1] + rd[1][2] + rd[1][3];
        const float logeps = logf(EPSF);
        const float log1m = logf(1.0f - EPSF);
        const float lossL = -(dL * log1m + ((float)Bn - dL) * logeps);
        const float lossR = -(dR * log1m + ((float)Bn - dR) * logeps);
        out[0] = (lossL + lossR) * 0.5f / (float)Bn;
    }
}

extern "C" void kernel_launch(void* const* d_in, const int* in_sizes, int n_in,
                              void* d_out, int out_size, void* d_ws, size_t ws_size,
                              hipStream_t stream) {
    (void)in_sizes; (void)n_in; (void)out_size; (void)ws_size;
    const float* left = (const float*)d_in[0];
    const float* right = (const float*)d_in[1];
    const float* temp = (const float*)d_in[2];

    char* ws = (char*)d_ws;
    unsigned char* lnb8 = (unsigned char*)ws;                       // 4 MiB
    unsigned char* rnb8 = (unsigned char*)(ws + (size_t)Bn * Dk);   // 4 MiB
    float* diag = (float*)(ws + 2 * (size_t)Bn * Dk);
    float* rowsum = diag + Bn;
    float* colsum = rowsum + Bn;

    nrm_kernel<<<Bn, 256, 0, stream>>>((const float4*)left, (const float4*)right,
                                       lnb8, rnb8, diag, rowsum, colsum);
    dim3 g2(Bn / 256, Bn / 128);
    gemm_sm_kernel<<<g2, 256, 0, stream>>>(lnb8, rnb8, temp, rowsum, colsum);
    loss_kernel<<<1, 256, 0, stream>>>(diag, rowsum, colsum, temp, (float*)d_out);
}